// Round 11
// baseline (280.932 us; speedup 1.0000x reference)
//
#include <hip/hip_runtime.h>
#include <stdint.h>

#define DEVINL __device__ __forceinline__

typedef __attribute__((ext_vector_type(8))) __bf16 bf16x8;
typedef __attribute__((ext_vector_type(4))) float f32x4;
typedef __attribute__((ext_vector_type(16))) float f32x16;
typedef __attribute__((ext_vector_type(4))) int i32x4;
typedef __attribute__((ext_vector_type(8))) int i32x8;

// ---------- helpers ----------
DEVINL unsigned short f2bf(float f) {
  union { float f; unsigned int u; } v; v.f = f;
  unsigned int u = v.u;
  return (unsigned short)((u + 0x7fffu + ((u >> 16) & 1u)) >> 16);  // RNE
}

// packed f32x2 -> bf16x2 via HW cvt (RNE, matches f2bf on normals)
DEVINL unsigned int cvtpk_bf16(float lo, float hi) {
  unsigned int r;
  asm("v_cvt_pk_bf16_f32 %0, %1, %2" : "=v"(r) : "v"(lo), "v"(hi));
  return r;
}

// float -> OCP e4m3 byte via HW cvt (gfx950 = OCP semantics)
DEVINL unsigned char f2fp8(float f) {
  return (unsigned char)(__builtin_amdgcn_cvt_pk_fp8_f32(f, f, 0, false) & 0xff);
}

DEVINL float sigm(float x) { return __builtin_amdgcn_rcpf(1.f + __expf(-x)); }
// tanh = 1 - 2/(1+e^{2x}); inf-safe both directions.
DEVINL float tanh_(float x) {
  return 1.f - 2.f * __builtin_amdgcn_rcpf(1.f + __expf(2.f * x));
}

// Operand-order ("tiled") global layout for gemm2's fp8 operands.
// 2048-B panel per (32-row block, 64-k block): [h=(k>>4)&1][g=(k>>5)&1][row&31][k&15]
DEVINL size_t opt_off(int row, int k) {
  return (size_t)((row >> 5) * 8 + (k >> 6)) * 2048 + ((k >> 4) & 1) * 1024 +
         ((k >> 5) & 1) * 512 + (row & 31) * 16 + (k & 15);
}

// async global->LDS 16B per lane; lds base wave-uniform, HW scatters lane i to base+i*16
#define GLD_LDS16(gptr, lptr)                                                  \
  __builtin_amdgcn_global_load_lds(                                            \
      (__attribute__((address_space(1))) void*)(gptr),                         \
      (__attribute__((address_space(3))) void*)(lptr), 16, 0, 0)

// ---------- prep: weight cvt + hvec only ----------
__global__ void prep_all(const float* __restrict__ W1, const float* __restrict__ Wih,
                         const float* __restrict__ W2, const float* __restrict__ Whh,
                         const float* __restrict__ hid, const float* __restrict__ bhh,
                         const float* __restrict__ bih,
                         unsigned short* __restrict__ W1b,
                         unsigned char* __restrict__ Wih8, unsigned short* __restrict__ W2b,
                         float* __restrict__ hvec) {
  const int bid = blockIdx.x, tid = threadIdx.x;
  if (bid < 1312) {
    // section B: weight conversion (one float4 per thread)
    const int i = bid * 256 + tid;
    if (i < 69632) {                       // W1 -> bf16
      float4 f = *(const float4*)(W1 + (size_t)i * 4);
      unsigned short u[4] = {f2bf(f.x), f2bf(f.y), f2bf(f.z), f2bf(f.w)};
      *(uint2*)(W1b + (size_t)i * 4) = *(uint2*)u;
    } else if (i < 69632 + 262144) {       // Wih -> fp8 e4m3 x16, operand-tiled layout
      const int off = i - 69632;
      const int row = off >> 7, col0 = (off & 127) * 4;  // 4 consecutive cols, same 16B chunk
      float4 f = *(const float4*)(Wih + (size_t)off * 4);
      int pk = __builtin_amdgcn_cvt_pk_fp8_f32(f.x * 16.f, f.y * 16.f, 0, false);
      pk = __builtin_amdgcn_cvt_pk_fp8_f32(f.z * 16.f, f.w * 16.f, pk, true);
      *(unsigned int*)(Wih8 + opt_off(row, col0)) = (unsigned int)pk;
    } else {                               // W2 -> bf16
      const int off = i - 331776;
      float4 f = *(const float4*)(W2 + (size_t)off * 4);
      unsigned short u[4] = {f2bf(f.x), f2bf(f.y), f2bf(f.z), f2bf(f.w)};
      *(uint2*)(W2b + (size_t)off * 4) = *(uint2*)u;
    }
  } else {
    // section C: hvec[j] = dot(W_hh[j,:], hid) + b_hh[j] + b_ih[j]
    const int j = (bid - 1312) * 4 + (tid >> 6);
    const int lane = tid & 63;
    const float* w = Whh + (size_t)j * 512;
    float s = 0.f;
    for (int k = lane; k < 512; k += 64) s += w[k] * hid[k];
    for (int off = 32; off; off >>= 1) s += __shfl_down(s, off, 64);
    if (lane == 0) hvec[j] = s + bhh[j] + bih[j];
  }
}

// ---------- GEMM1 v3: BARRIER-FREE, both operands direct-to-register ----------
// X8 = fp8(relu(concat(obs,act) @ W1^T + b1) * 8), operand-tiled out.
// R10's fused version stalled on a vmcnt(0)+barrier per kt (block-wide full
// memory latency x17: MfmaUtil 9.4%, VALUBusy 7.9%). LDS bought nothing here:
// W1b (557 KB) is L2-resident and obs rows are only re-read 4x (L2 absorbs —
// FETCH showed 85% L2-hit). So: NO LDS, NO barriers.
// Fragment mapping (verified vs the old LDS path, bit-identical): lane(fr,q)
//   A[i]: row m0+wr+i*16+fr, k = kt*32 + q*8..+7  (8 fp32 -> cvt bf16x8)
//   B[j]: row n0+wc+j*16+fr, k = kt*32 + q*8..+7  (one b128 from W1b)
// 2-set register pipeline: set kt&1 is consumed (A cvt'd to fresh regs, B fed
// to MFMAs), then immediately re-loaded with kt+2 -> ~2-kt latency lead; the
// fully-unrolled loop keeps all indexing compile-time (no scratch).
__global__ __launch_bounds__(256, 2) void gemm1_relu(
    const float* __restrict__ obs,           // [32768,512] fp32
    const float* __restrict__ act,           // [32768,32] fp32
    const unsigned short* __restrict__ W1b,  // [512,544] bf16
    const float* __restrict__ b1,            // [512]
    unsigned char* __restrict__ X8) {        // [32768,512] fp8 (x8, operand-tiled)
  const int tid = threadIdx.x, wave = tid >> 6, lane = tid & 63;
  const int id = blockIdx.x, xcd = id & 7, slot = id >> 3;  // 1024 blocks
  const int m0 = (xcd * 32 + (slot >> 2)) * 128;            // 256 m-tiles
  const int n0 = (slot & 3) * 128;                          // 4 n-tiles
  const int wr = (wave >> 1) * 64, wc = (wave & 1) * 64;
  const int fr = lane & 15, q = lane >> 4;
  f32x4 acc[4][4] = {};

  // per-lane row pointers (constant-indexed under full unroll)
  const float* aro[4];
  const float* ara[4];
  const unsigned short* brw[4];
#pragma unroll
  for (int i = 0; i < 4; ++i) {
    aro[i] = obs + (size_t)(m0 + wr + i * 16 + fr) * 512 + q * 8;
    ara[i] = act + (size_t)(m0 + wr + i * 16 + fr) * 32 + q * 8;
    brw[i] = W1b + (size_t)(n0 + wc + i * 16 + fr) * 544 + q * 8;
  }

  float4 Af[2][4][2];  // [set][i][half] fp32 A stage
  bf16x8 Bf[2][4];     // [set][j] B frags

#define LOADSET(s, K)                                                          \
  do {                                                                         \
    _Pragma("unroll")                                                          \
    for (int i_ = 0; i_ < 4; ++i_) {                                           \
      const float* p_ = ((K) < 16) ? (aro[i_] + (K) * 32) : ara[i_];           \
      Af[s][i_][0] = *(const float4*)p_;                                       \
      Af[s][i_][1] = *(const float4*)(p_ + 4);                                 \
      Bf[s][i_] = *(const bf16x8*)(brw[i_] + (K) * 32);                        \
    }                                                                          \
  } while (0)

  LOADSET(0, 0);
  LOADSET(1, 1);

#pragma unroll
  for (int kt = 0; kt < 17; ++kt) {
    const int s = kt & 1;
    bf16x8 a[4];
#pragma unroll
    for (int i = 0; i < 4; ++i) {  // cvt (compiler inserts counted vmcnt here)
      unsigned int w_[4] = {cvtpk_bf16(Af[s][i][0].x, Af[s][i][0].y),
                            cvtpk_bf16(Af[s][i][0].z, Af[s][i][0].w),
                            cvtpk_bf16(Af[s][i][1].x, Af[s][i][1].y),
                            cvtpk_bf16(Af[s][i][1].z, Af[s][i][1].w)};
      a[i] = *(bf16x8*)w_;
    }
#pragma unroll
    for (int i = 0; i < 4; ++i)
#pragma unroll
      for (int j = 0; j < 4; ++j)
        acc[i][j] = __builtin_amdgcn_mfma_f32_16x16x32_bf16(a[i], Bf[s][j], acc[i][j], 0, 0, 0);
    if (kt + 2 < 17) LOADSET(s, kt + 2);  // re-issue set after its consumers
  }
#undef LOADSET

  const int rbase = q * 4, cn = fr;
#pragma unroll
  for (int i = 0; i < 4; ++i)
#pragma unroll
    for (int j = 0; j < 4; ++j) {
      const int gn = n0 + wc + j * 16 + cn;
      const float bias = b1[gn];
#pragma unroll
      for (int r = 0; r < 4; ++r) {
        const int gm = m0 + wr + i * 16 + rbase + r;
        float v = acc[i][j][r] + bias;
        v = v > 0.f ? v : 0.f;
        X8[opt_off(gm, gn)] = f2fp8(v * 8.f);
      }
    }
}

// ---------- GEMM2 MX-fp8 32x32x64: B-in-LDS-once + deep-prefetch A + LSTM ------
// (R7 structure verbatim -- 47.5-48.8 us known-good.)
__global__ __launch_bounds__(256, 2) void gemm2_lstm(
    const unsigned char* __restrict__ X8,    // [32768,512] fp8, operand-tiled
    const unsigned char* __restrict__ Wih8,  // [2048,512] fp8, operand-tiled
    const float* __restrict__ hvec,          // [2048]
    const float* __restrict__ cell,          // [512]
    unsigned short* __restrict__ H,          // [32768,512] bf16 out
    float* __restrict__ hlast,               // [512] fp32 out
    float* __restrict__ clast) {             // [512] fp32 out
  __shared__ __align__(16) unsigned char Bs[4 * 16384];      // 64 KB: [quad][kt*2048+h*1024]
  const int tid = threadIdx.x, wave = tid >> 6, lane = tid & 63;
  const int id = blockIdx.x, xcd = id & 7, slot = id >> 3;  // 2048 blocks
  const int m0 = (xcd * 16 + (slot >> 4)) * 256;            // 128 m-tiles
  const int n0 = (slot & 15) * 32;                          // 16 quadrant-col tiles
  const int r31 = lane & 31, g2 = lane >> 5;
  const int voff = g2 * 512 + r31 * 16;  // lane's operand offset within a panel

  // ---- prologue: stage ALL of B (this block's 4 quads x 8 kt) into LDS ----
  {
    const unsigned char* bsrc =
        Wih8 + (size_t)(wave * 16 + (n0 >> 5)) * 16384 + lane * 16;
#pragma unroll
    for (int s = 0; s < 16; ++s)
      GLD_LDS16(bsrc + s * 1024, &Bs[wave * 16384 + s * 1024]);
  }

  // ---- A prefetch (triple-buffered, depth 2) ----
  const unsigned char* pa = X8 + (size_t)((m0 >> 5) + wave * 2) * 16384 + voff;
  i32x8 Aa[3], Ab[3];
#define LDA(buf, kt)                                                           \
  do {                                                                         \
    i32x4 lo0 = *(const i32x4*)(pa + (kt) * 2048);                             \
    i32x4 hi0 = *(const i32x4*)(pa + (kt) * 2048 + 1024);                      \
    Aa[buf] = __builtin_shufflevector(lo0, hi0, 0, 1, 2, 3, 4, 5, 6, 7);       \
    i32x4 lo1 = *(const i32x4*)(pa + 16384 + (kt) * 2048);                     \
    i32x4 hi1 = *(const i32x4*)(pa + 16384 + (kt) * 2048 + 1024);              \
    Ab[buf] = __builtin_shufflevector(lo1, hi1, 0, 1, 2, 3, 4, 5, 6, 7);       \
  } while (0)

#define MFMA_MX(acc_, a_, b_)                                                  \
  acc_ = __builtin_amdgcn_mfma_scale_f32_32x32x64_f8f6f4(                      \
      a_, b_, acc_, 0, 0, 0, 0x7f7f7f7f, 0, 0x7f7f7f7f)

  LDA(0, 0);
  LDA(1, 1);
  __syncthreads();  // B visible; only barrier in kernel

  // 8 accumulators: [frag f=0,1][gate quadrant 0..3]
  f32x16 acc00 = {}, acc01 = {}, acc02 = {}, acc03 = {};
  f32x16 acc10 = {}, acc11 = {}, acc12 = {}, acc13 = {};

#pragma unroll
  for (int kt = 0; kt < 8; ++kt) {
    const int cur = kt % 3, nx = (kt + 2) % 3;  // compile-time after unroll
    if (kt < 6) LDA(nx, kt + 2);                // issue-early: 2-kt lead on HBM
    i32x8 B0, B1, B2, B3;
    {
      const unsigned char* bb = &Bs[kt * 2048 + lane * 16];
      i32x4 l0 = *(const i32x4*)(bb);
      i32x4 h0 = *(const i32x4*)(bb + 1024);
      i32x4 l1 = *(const i32x4*)(bb + 16384);
      i32x4 h1 = *(const i32x4*)(bb + 16384 + 1024);
      i32x4 l2 = *(const i32x4*)(bb + 32768);
      i32x4 h2 = *(const i32x4*)(bb + 32768 + 1024);
      i32x4 l3 = *(const i32x4*)(bb + 49152);
      i32x4 h3 = *(const i32x4*)(bb + 49152 + 1024);
      B0 = __builtin_shufflevector(l0, h0, 0, 1, 2, 3, 4, 5, 6, 7);
      B1 = __builtin_shufflevector(l1, h1, 0, 1, 2, 3, 4, 5, 6, 7);
      B2 = __builtin_shufflevector(l2, h2, 0, 1, 2, 3, 4, 5, 6, 7);
      B3 = __builtin_shufflevector(l3, h3, 0, 1, 2, 3, 4, 5, 6, 7);
    }
    MFMA_MX(acc00, Aa[cur], B0); MFMA_MX(acc01, Aa[cur], B1);
    MFMA_MX(acc02, Aa[cur], B2); MFMA_MX(acc03, Aa[cur], B3);
    MFMA_MX(acc10, Ab[cur], B0); MFMA_MX(acc11, Ab[cur], B1);
    MFMA_MX(acc12, Ab[cur], B2); MFMA_MX(acc13, Ab[cur], B3);
  }
#undef LDA
#undef MFMA_MX

  const int gn = n0 + r31;  // column in [0,512)
  const float hv_i = hvec[gn];
  const float hv_f = hvec[gn + 512];
  const float hv_g = hvec[gn + 1024];
  const float hv_o = hvec[gn + 1536];
  const float cprev = cell[gn];
  constexpr float S = 1.f / 128.f;  // undo x8 (X) * x16 (Wih)

#define EPILOG(F, ai, af, ag, ao)                                              \
  _Pragma("unroll")                                                            \
  for (int rg = 0; rg < 4; ++rg) {                                             \
    _Pragma("unroll")                                                          \
    for (int rr = 0; rr < 4; ++rr) {                                           \
      const int reg = rg * 4 + rr;                                             \
      const int gm = m0 + wave * 64 + (F) * 32 + rr + rg * 8 + g2 * 4;         \
      float si = sigm(ai[reg] * S + hv_i);                                     \
      float sf = sigm(af[reg] * S + hv_f);                                     \
      float tg = tanh_(ag[reg] * S + hv_g);                                    \
      float so = sigm(ao[reg] * S + hv_o);                                     \
      float cnew = sf * cprev + si * tg;                                       \
      float hnew = so * tanh_(cnew);                                           \
      H[(size_t)gm * 512 + gn] = f2bf(hnew);                                   \
      if (gm == 32767) { hlast[gn] = hnew; clast[gn] = cnew; }                 \
    }                                                                          \
  }

  EPILOG(0, acc00, acc01, acc02, acc03)
  EPILOG(1, acc10, acc11, acc12, acc13)
#undef EPILOG
}

// ---------- GEMM3 v2: Q = H @ W2^T + b2 -- barrier-free streaming ----------
__global__ __launch_bounds__(256, 2) void gemm3(
    const unsigned short* __restrict__ H,    // [32768,512] bf16
    const unsigned short* __restrict__ W2b,  // [32,512] bf16
    const float* __restrict__ b2,            // [32]
    float* __restrict__ Q) {                 // [32768,32] fp32
  constexpr int LDW = 520;
  __shared__ __align__(16) unsigned short Ws[32 * LDW];      // 32.5 KB
  const int tid = threadIdx.x, wave = tid >> 6, lane = tid & 63;
  const int id = blockIdx.x;                                 // 512 blocks
  const int m0 = ((id & 7) * 64 + (id >> 3)) * 64 + wave * 16;  // 16 rows/wave
  for (int c = tid; c < 2048; c += 256) {
    const int row = c >> 6, col8 = c & 63;
    *(uint4*)&Ws[row * LDW + col8 * 8] = *(const uint4*)(W2b + row * 512 + col8 * 8);
  }
  __syncthreads();  // only barrier in kernel

  const int fr = lane & 15, q = lane >> 4;
  f32x4 acc[2] = {};
  const unsigned short* pH = H + (size_t)(m0 + fr) * 512 + q * 8;
#pragma unroll
  for (int kt = 0; kt < 16; ++kt) {
    const int k0 = kt * 32;
    bf16x8 a  = *(const bf16x8*)(pH + k0);
    bf16x8 b0 = *(const bf16x8*)&Ws[fr * LDW + k0 + q * 8];
    bf16x8 b1 = *(const bf16x8*)&Ws[(16 + fr) * LDW + k0 + q * 8];
    acc[0] = __builtin_amdgcn_mfma_f32_16x16x32_bf16(a, b0, acc[0], 0, 0, 0);
    acc[1] = __builtin_amdgcn_mfma_f32_16x16x32_bf16(a, b1, acc[1], 0, 0, 0);
  }

  const int rbase = q * 4;
#pragma unroll
  for (int j = 0; j < 2; ++j) {
    const int gn = j * 16 + fr;
    const float bias = b2[gn];
#pragma unroll
    for (int r = 0; r < 4; ++r) {
      const int gm = m0 + rbase + r;
      Q[(size_t)gm * 32 + gn] = acc[j][r] + bias;
    }
  }
}

// ---------- launch ----------
extern "C" void kernel_launch(void* const* d_in, const int* in_sizes, int n_in,
                              void* d_out, int out_size, void* d_ws, size_t ws_size,
                              hipStream_t stream) {
  const float* obs  = (const float*)d_in[0];
  const float* act  = (const float*)d_in[1];
  const float* hid  = (const float*)d_in[2];
  const float* cell = (const float*)d_in[3];
  const float* W1   = (const float*)d_in[4];
  const float* b1   = (const float*)d_in[5];
  const float* Wih  = (const float*)d_in[6];
  const float* bih  = (const float*)d_in[7];
  const float* Whh  = (const float*)d_in[8];
  const float* bhh  = (const float*)d_in[9];
  const float* W2   = (const float*)d_in[10];
  const float* b2   = (const float*)d_in[11];
  float* out = (float*)d_out;

  char* ws = (char*)d_ws;
  unsigned short* H    = (unsigned short*)(ws);              // [B,512] bf16 (33,554,432 B)
  unsigned char*  X8   = (unsigned char*)(ws + 35651584);    // [B,512] fp8 tiled (16,777,216 B)
  unsigned short* W1b  = (unsigned short*)(ws + 52428800);   // 557,056 B
  unsigned char*  Wih8 = (unsigned char*)(ws + 52985856);    // 1,048,576 B
  unsigned short* W2b  = (unsigned short*)(ws + 54034432);   // 32,768 B
  float*          hvec = (float*)(ws + 54067200);            // 8,192 B

  prep_all<<<1824, 256, 0, stream>>>(W1, Wih, W2, Whh, hid, bhh, bih,
                                     W1b, Wih8, W2b, hvec);
  gemm1_relu<<<1024, 256, 0, stream>>>(obs, act, W1b, b1, X8);
  gemm2_lstm<<<2048, 256, 0, stream>>>(X8, Wih8, hvec, cell, H,
                                       out + 32768 * 32,
                                       out + 32768 * 32 + 512);
  gemm3<<<512, 256, 0, stream>>>(H, W2b, b2, out);
}

// Round 12
// 205.959 us; speedup vs baseline: 1.3640x; 1.3640x over previous
//
#include <hip/hip_runtime.h>
#include <stdint.h>

#define DEVINL __device__ __forceinline__

typedef __attribute__((ext_vector_type(8))) __bf16 bf16x8;
typedef __attribute__((ext_vector_type(4))) float f32x4;
typedef __attribute__((ext_vector_type(16))) float f32x16;
typedef __attribute__((ext_vector_type(4))) int i32x4;
typedef __attribute__((ext_vector_type(8))) int i32x8;

// ---------- helpers ----------
DEVINL unsigned short f2bf(float f) {
  union { float f; unsigned int u; } v; v.f = f;
  unsigned int u = v.u;
  return (unsigned short)((u + 0x7fffu + ((u >> 16) & 1u)) >> 16);  // RNE
}

// packed f32x2 -> bf16x2 via HW cvt (RNE, matches f2bf on normals)
DEVINL unsigned int cvtpk_bf16(float lo, float hi) {
  unsigned int r;
  asm("v_cvt_pk_bf16_f32 %0, %1, %2" : "=v"(r) : "v"(lo), "v"(hi));
  return r;
}

// float -> OCP e4m3 byte via HW cvt (gfx950 = OCP semantics)
DEVINL unsigned char f2fp8(float f) {
  return (unsigned char)(__builtin_amdgcn_cvt_pk_fp8_f32(f, f, 0, false) & 0xff);
}

DEVINL float sigm(float x) { return __builtin_amdgcn_rcpf(1.f + __expf(-x)); }
// tanh = 1 - 2/(1+e^{2x}); inf-safe both directions.
DEVINL float tanh_(float x) {
  return 1.f - 2.f * __builtin_amdgcn_rcpf(1.f + __expf(2.f * x));
}

// Operand-order ("tiled") global layout for gemm2's fp8 operands.
// 2048-B panel per (32-row block, 64-k block): [h=(k>>4)&1][g=(k>>5)&1][row&31][k&15]
DEVINL size_t opt_off(int row, int k) {
  return (size_t)((row >> 5) * 8 + (k >> 6)) * 2048 + ((k >> 4) & 1) * 1024 +
         ((k >> 5) & 1) * 512 + (row & 31) * 16 + (k & 15);
}

// async global->LDS 16B per lane; lds base wave-uniform, HW scatters lane i to base+i*16
#define GLD_LDS16(gptr, lptr)                                                  \
  __builtin_amdgcn_global_load_lds(                                            \
      (__attribute__((address_space(1))) void*)(gptr),                         \
      (__attribute__((address_space(3))) void*)(lptr), 16, 0, 0)

// counted-vmcnt stage barrier: drains the 2 B gload_lds (older) + publishes
// ds_writes, leaves the 8 A-prefetch reg-loads (newer) in flight.
#define STGBAR_8 asm volatile("s_waitcnt vmcnt(8) lgkmcnt(0)\n\ts_barrier" ::: "memory")
#define STGBAR_0 asm volatile("s_waitcnt vmcnt(0) lgkmcnt(0)\n\ts_barrier" ::: "memory")

// bf16-path XOR swizzle (measured 0-conflict): staging chunk c takes source
// chunk (c&3)^((c>>3)&3); read koff = (q ^ ((fr>>1)&3)).
DEVINL int swz_col(int c) { return ((c & 3) ^ ((c >> 3) & 3)) * 8; }   // *8 shorts = 16B

// ---------- prep: weight cvt + hvec only ----------
__global__ void prep_all(const float* __restrict__ W1, const float* __restrict__ Wih,
                         const float* __restrict__ W2, const float* __restrict__ Whh,
                         const float* __restrict__ hid, const float* __restrict__ bhh,
                         const float* __restrict__ bih,
                         unsigned short* __restrict__ W1b,
                         unsigned char* __restrict__ Wih8, unsigned short* __restrict__ W2b,
                         float* __restrict__ hvec) {
  const int bid = blockIdx.x, tid = threadIdx.x;
  if (bid < 1312) {
    // section B: weight conversion (one float4 per thread)
    const int i = bid * 256 + tid;
    if (i < 69632) {                       // W1 -> bf16
      float4 f = *(const float4*)(W1 + (size_t)i * 4);
      unsigned short u[4] = {f2bf(f.x), f2bf(f.y), f2bf(f.z), f2bf(f.w)};
      *(uint2*)(W1b + (size_t)i * 4) = *(uint2*)u;
    } else if (i < 69632 + 262144) {       // Wih -> fp8 e4m3 x16, operand-tiled layout
      const int off = i - 69632;
      const int row = off >> 7, col0 = (off & 127) * 4;  // 4 consecutive cols, same 16B chunk
      float4 f = *(const float4*)(Wih + (size_t)off * 4);
      int pk = __builtin_amdgcn_cvt_pk_fp8_f32(f.x * 16.f, f.y * 16.f, 0, false);
      pk = __builtin_amdgcn_cvt_pk_fp8_f32(f.z * 16.f, f.w * 16.f, pk, true);
      *(unsigned int*)(Wih8 + opt_off(row, col0)) = (unsigned int)pk;
    } else {                               // W2 -> bf16
      const int off = i - 331776;
      float4 f = *(const float4*)(W2 + (size_t)off * 4);
      unsigned short u[4] = {f2bf(f.x), f2bf(f.y), f2bf(f.z), f2bf(f.w)};
      *(uint2*)(W2b + (size_t)off * 4) = *(uint2*)u;
    }
  } else {
    // section C: hvec[j] = dot(W_hh[j,:], hid) + b_hh[j] + b_ih[j]
    const int j = (bid - 1312) * 4 + (tid >> 6);
    const int lane = tid & 63;
    const float* w = Whh + (size_t)j * 512;
    float s = 0.f;
    for (int k = lane; k < 512; k += 64) s += w[k] * hid[k];
    for (int off = 32; off; off >>= 1) s += __shfl_down(s, off, 64);
    if (lane == 0) hvec[j] = s + bhh[j] + bih[j];
  }
}

// ---------- GEMM1 v4: original LDS pipeline, A fused from obs/act ----------
// X8 = fp8(relu(concat(obs,act) @ W1^T + b1) * 8), operand-tiled out.
// Minimal delta from the known-good A0-based kernel: SAME LDS layout, swizzle,
// read side, MFMA phase, double-buffer. Only the A staging changed:
// gload_lds(A0) -> {8 reg loads from obs/act (2-TILE lead), v_cvt_pk_bf16_f32,
// ds_write_b128 at chunk*16 (lane-linear, conflict-free)}.
// Counted-vmcnt single barrier per kt:
//   issue B gload(kt+1) -> sched_barrier(0) (pins order) -> issue A regs(kt+2)
//   -> MFMAs(kt) -> cvt+ds_write A(kt+1) (compiler waits its loads, ~1 iter old)
//   -> vmcnt(8)+lgkmcnt(0)+s_barrier: drains B(kt+1) (older than the 8 A loads),
//      publishes writes, LEAVES A(kt+2) in flight.
// Failures this replaces: R10 (vmcnt(0) barrier drained prefetch, 72us),
// R11 (no-LDS variant spilled operand arrays to scratch, 130us).
__global__ __launch_bounds__(256, 2) void gemm1_relu(
    const float* __restrict__ obs,           // [32768,512] fp32
    const float* __restrict__ act,           // [32768,32] fp32
    const unsigned short* __restrict__ W1b,  // [512,544] bf16
    const float* __restrict__ b1,            // [512]
    unsigned char* __restrict__ X8) {        // [32768,512] fp8 (x8, operand-tiled)
  __shared__ __align__(16) unsigned short As[2][4096];  // 128x32 bf16 per buf (8 KB)
  __shared__ __align__(16) unsigned short Bs[2][4096];
  const int tid = threadIdx.x, wave = tid >> 6, lane = tid & 63;
  const int id = blockIdx.x, xcd = id & 7, slot = id >> 3;  // 1024 blocks
  const int m0 = (xcd * 32 + (slot >> 2)) * 128;            // 256 m-tiles
  const int n0 = (slot & 3) * 128;                          // 4 n-tiles
  const int wr = (wave >> 1) * 64, wc = (wave & 1) * 64;
  f32x4 acc[4][4] = {};

  const int c0 = tid, c1 = tid + 256;            // this thread's 2 A-chunks
  const int r0 = c0 >> 2, r1 = c1 >> 2;          // tile rows
  const int sw0 = swz_col(c0), sw1 = swz_col(c1);
  const float* pObs0 = obs + (size_t)(m0 + r0) * 512 + sw0;
  const float* pObs1 = obs + (size_t)(m0 + r1) * 512 + sw1;
  const float* pAct0 = act + (size_t)(m0 + r0) * 32 + sw0;
  const float* pAct1 = act + (size_t)(m0 + r1) * 32 + sw1;
  const unsigned short* pB0 = W1b + (size_t)(n0 + r0) * 544 + sw0;
  const unsigned short* pB1 = W1b + (size_t)(n0 + r1) * 544 + sw1;
  const int fr = lane & 15, q = lane >> 4;
  const int koff = (q ^ ((fr >> 1) & 3)) * 8;

  float4 Afs[2][4];  // [set][lo0,hi0,lo1,hi1] — static-indexed under full unroll

#define LOADA(s, K)                                                            \
  do {                                                                         \
    const float* s0_ = ((K) < 16) ? (pObs0 + (K) * 32) : pAct0;                \
    const float* s1_ = ((K) < 16) ? (pObs1 + (K) * 32) : pAct1;                \
    Afs[s][0] = *(const float4*)s0_;  Afs[s][1] = *(const float4*)(s0_ + 4);   \
    Afs[s][2] = *(const float4*)s1_;  Afs[s][3] = *(const float4*)(s1_ + 4);   \
  } while (0)

#define GLDB(buf)                                                              \
  do {                                                                         \
    GLD_LDS16(pB0, &Bs[(buf)][wave * 512]);                                    \
    GLD_LDS16(pB1, &Bs[(buf)][2048 + wave * 512]);                             \
    pB0 += 32; pB1 += 32;                                                      \
  } while (0)

#define CVTWR(s, buf)                                                          \
  do {                                                                         \
    unsigned int w0_[4] = {cvtpk_bf16(Afs[s][0].x, Afs[s][0].y),               \
                           cvtpk_bf16(Afs[s][0].z, Afs[s][0].w),               \
                           cvtpk_bf16(Afs[s][1].x, Afs[s][1].y),               \
                           cvtpk_bf16(Afs[s][1].z, Afs[s][1].w)};              \
    *(uint4*)&As[(buf)][c0 * 8] = *(uint4*)w0_;                                \
    unsigned int w1_[4] = {cvtpk_bf16(Afs[s][2].x, Afs[s][2].y),               \
                           cvtpk_bf16(Afs[s][2].z, Afs[s][2].w),               \
                           cvtpk_bf16(Afs[s][3].x, Afs[s][3].y),               \
                           cvtpk_bf16(Afs[s][3].z, Afs[s][3].w)};              \
    *(uint4*)&As[(buf)][c1 * 8] = *(uint4*)w1_;                                \
  } while (0)

  // prologue: B(t0) first (oldest in vmem queue), then A sets for t0,t1.
  GLDB(0);
  __builtin_amdgcn_sched_barrier(0);  // keep B issue ahead of A loads
  LOADA(0, 0);
  LOADA(1, 1);
  CVTWR(0, 0);   // compiler waits set0's loads only (vmcnt leaves set1)
  STGBAR_8;      // drains B(t0) (oldest); set1's 8 loads stay in flight

#pragma unroll
  for (int kt = 0; kt < 17; ++kt) {
    const int buf = kt & 1;
    if (kt + 1 < 17) {
      GLDB(buf ^ 1);
      __builtin_amdgcn_sched_barrier(0);  // B(kt+1) older than A(kt+2) in queue
    }
    if (kt + 2 < 17) LOADA(kt & 1, kt + 2);  // reload the set freed last iter
    const unsigned short* as = As[buf];
    const unsigned short* bs = Bs[buf];
    bf16x8 a[4], b[4];
#pragma unroll
    for (int i = 0; i < 4; ++i) a[i] = *(const bf16x8*)&as[(wr + i * 16 + fr) * 32 + koff];
#pragma unroll
    for (int j = 0; j < 4; ++j) b[j] = *(const bf16x8*)&bs[(wc + j * 16 + fr) * 32 + koff];
#pragma unroll
    for (int i = 0; i < 4; ++i)
#pragma unroll
      for (int j = 0; j < 4; ++j)
        acc[i][j] = __builtin_amdgcn_mfma_f32_16x16x32_bf16(a[i], b[j], acc[i][j], 0, 0, 0);
    if (kt + 1 < 17) {
      CVTWR((kt + 1) & 1, buf ^ 1);  // set's loads are ~1 full iter old
      if (kt + 2 < 17) STGBAR_8;     // leave A(kt+2) in flight
      else             STGBAR_0;     // kt=15: nothing to preserve
    }
  }
#undef LOADA
#undef GLDB
#undef CVTWR

  const int rbase = q * 4, cn = fr;
#pragma unroll
  for (int i = 0; i < 4; ++i)
#pragma unroll
    for (int j = 0; j < 4; ++j) {
      const int gn = n0 + wc + j * 16 + cn;
      const float bias = b1[gn];
#pragma unroll
      for (int r = 0; r < 4; ++r) {
        const int gm = m0 + wr + i * 16 + rbase + r;
        float v = acc[i][j][r] + bias;
        v = v > 0.f ? v : 0.f;
        X8[opt_off(gm, gn)] = f2fp8(v * 8.f);
      }
    }
}

// ---------- GEMM2 MX-fp8 32x32x64: B-in-LDS-once + deep-prefetch A + LSTM ------
// (R7 structure verbatim -- 47.5-48.8 us known-good.)
__global__ __launch_bounds__(256, 2) void gemm2_lstm(
    const unsigned char* __restrict__ X8,    // [32768,512] fp8, operand-tiled
    const unsigned char* __restrict__ Wih8,  // [2048,512] fp8, operand-tiled
    const float* __restrict__ hvec,          // [2048]
    const float* __restrict__ cell,          // [512]
    unsigned short* __restrict__ H,          // [32768,512] bf16 out
    float* __restrict__ hlast,               // [512] fp32 out
    float* __restrict__ clast) {             // [512] fp32 out
  __shared__ __align__(16) unsigned char Bs[4 * 16384];      // 64 KB: [quad][kt*2048+h*1024]
  const int tid = threadIdx.x, wave = tid >> 6, lane = tid & 63;
  const int id = blockIdx.x, xcd = id & 7, slot = id >> 3;  // 2048 blocks
  const int m0 = (xcd * 16 + (slot >> 4)) * 256;            // 128 m-tiles
  const int n0 = (slot & 15) * 32;                          // 16 quadrant-col tiles
  const int r31 = lane & 31, g2 = lane >> 5;
  const int voff = g2 * 512 + r31 * 16;  // lane's operand offset within a panel

  // ---- prologue: stage ALL of B (this block's 4 quads x 8 kt) into LDS ----
  {
    const unsigned char* bsrc =
        Wih8 + (size_t)(wave * 16 + (n0 >> 5)) * 16384 + lane * 16;
#pragma unroll
    for (int s = 0; s < 16; ++s)
      GLD_LDS16(bsrc + s * 1024, &Bs[wave * 16384 + s * 1024]);
  }

  // ---- A prefetch (triple-buffered, depth 2) ----
  const unsigned char* pa = X8 + (size_t)((m0 >> 5) + wave * 2) * 16384 + voff;
  i32x8 Aa[3], Ab[3];
#define LDA(buf, kt)                                                           \
  do {                                                                         \
    i32x4 lo0 = *(const i32x4*)(pa + (kt) * 2048);                             \
    i32x4 hi0 = *(const i32x4*)(pa + (kt) * 2048 + 1024);                      \
    Aa[buf] = __builtin_shufflevector(lo0, hi0, 0, 1, 2, 3, 4, 5, 6, 7);       \
    i32x4 lo1 = *(const i32x4*)(pa + 16384 + (kt) * 2048);                     \
    i32x4 hi1 = *(const i32x4*)(pa + 16384 + (kt) * 2048 + 1024);              \
    Ab[buf] = __builtin_shufflevector(lo1, hi1, 0, 1, 2, 3, 4, 5, 6, 7);       \
  } while (0)

#define MFMA_MX(acc_, a_, b_)                                                  \
  acc_ = __builtin_amdgcn_mfma_scale_f32_32x32x64_f8f6f4(                      \
      a_, b_, acc_, 0, 0, 0, 0x7f7f7f7f, 0, 0x7f7f7f7f)

  LDA(0, 0);
  LDA(1, 1);
  __syncthreads();  // B visible; only barrier in kernel

  // 8 accumulators: [frag f=0,1][gate quadrant 0..3]
  f32x16 acc00 = {}, acc01 = {}, acc02 = {}, acc03 = {};
  f32x16 acc10 = {}, acc11 = {}, acc12 = {}, acc13 = {};

#pragma unroll
  for (int kt = 0; kt < 8; ++kt) {
    const int cur = kt % 3, nx = (kt + 2) % 3;  // compile-time after unroll
    if (kt < 6) LDA(nx, kt + 2);                // issue-early: 2-kt lead on HBM
    i32x8 B0, B1, B2, B3;
    {
      const unsigned char* bb = &Bs[kt * 2048 + lane * 16];
      i32x4 l0 = *(const i32x4*)(bb);
      i32x4 h0 = *(const i32x4*)(bb + 1024);
      i32x4 l1 = *(const i32x4*)(bb + 16384);
      i32x4 h1 = *(const i32x4*)(bb + 16384 + 1024);
      i32x4 l2 = *(const i32x4*)(bb + 32768);
      i32x4 h2 = *(const i32x4*)(bb + 32768 + 1024);
      i32x4 l3 = *(const i32x4*)(bb + 49152);
      i32x4 h3 = *(const i32x4*)(bb + 49152 + 1024);
      B0 = __builtin_shufflevector(l0, h0, 0, 1, 2, 3, 4, 5, 6, 7);
      B1 = __builtin_shufflevector(l1, h1, 0, 1, 2, 3, 4, 5, 6, 7);
      B2 = __builtin_shufflevector(l2, h2, 0, 1, 2, 3, 4, 5, 6, 7);
      B3 = __builtin_shufflevector(l3, h3, 0, 1, 2, 3, 4, 5, 6, 7);
    }
    MFMA_MX(acc00, Aa[cur], B0); MFMA_MX(acc01, Aa[cur], B1);
    MFMA_MX(acc02, Aa[cur], B2); MFMA_MX(acc03, Aa[cur], B3);
    MFMA_MX(acc10, Ab[cur], B0); MFMA_MX(acc11, Ab[cur], B1);
    MFMA_MX(acc12, Ab[cur], B2); MFMA_MX(acc13, Ab[cur], B3);
  }
#undef LDA
#undef MFMA_MX

  const int gn = n0 + r31;  // column in [0,512)
  const float hv_i = hvec[gn];
  const float hv_f = hvec[gn + 512];
  const float hv_g = hvec[gn + 1024];
  const float hv_o = hvec[gn + 1536];
  const float cprev = cell[gn];
  constexpr float S = 1.f / 128.f;  // undo x8 (X) * x16 (Wih)

#define EPILOG(F, ai, af, ag, ao)                                              \
  _Pragma("unroll")                                                            \
  for (int rg = 0; rg < 4; ++rg) {                                             \
    _Pragma("unroll")                                                          \
    for (int rr = 0; rr < 4; ++rr) {                                           \
      const int reg = rg * 4 + rr;                                             \
      const int gm = m0 + wave * 64 + (F) * 32 + rr + rg * 8 + g2 * 4;         \
      float si = sigm(ai[reg] * S + hv_i);                                     \
      float sf = sigm(af[reg] * S + hv_f);                                     \
      float tg = tanh_(ag[reg] * S + hv_g);                                    \
      float so = sigm(ao[reg] * S + hv_o);                                     \
      float cnew = sf * cprev + si * tg;                                       \
      float hnew = so * tanh_(cnew);                                           \
      H[(size_t)gm * 512 + gn] = f2bf(hnew);                                   \
      if (gm == 32767) { hlast[gn] = hnew; clast[gn] = cnew; }                 \
    }                                                                          \
  }

  EPILOG(0, acc00, acc01, acc02, acc03)
  EPILOG(1, acc10, acc11, acc12, acc13)
#undef EPILOG
}

// ---------- GEMM3 v2: Q = H @ W2^T + b2 -- barrier-free streaming ----------
__global__ __launch_bounds__(256, 2) void gemm3(
    const unsigned short* __restrict__ H,    // [32768,512] bf16
    const unsigned short* __restrict__ W2b,  // [32,512] bf16
    const float* __restrict__ b2,            // [32]
    float* __restrict__ Q) {                 // [32768,32] fp32
  constexpr int LDW = 520;
  __shared__ __align__(16) unsigned short Ws[32 * LDW];      // 32.5 KB
  const int tid = threadIdx.x, wave = tid >> 6, lane = tid & 63;
  const int id = blockIdx.x;                                 // 512 blocks
  const int m0 = ((id & 7) * 64 + (id >> 3)) * 64 + wave * 16;  // 16 rows/wave
  for (int c = tid; c < 2048; c += 256) {
    const int row = c >> 6, col8 = c & 63;
    *(uint4*)&Ws[row * LDW + col8 * 8] = *(const uint4*)(W2b + row * 512 + col8 * 8);
  }
  __syncthreads();  // only barrier in kernel

  const int fr = lane & 15, q = lane >> 4;
  f32x4 acc[2] = {};
  const unsigned short* pH = H + (size_t)(m0 + fr) * 512 + q * 8;
#pragma unroll
  for (int kt = 0; kt < 16; ++kt) {
    const int k0 = kt * 32;
    bf16x8 a  = *(const bf16x8*)(pH + k0);
    bf16x8 b0 = *(const bf16x8*)&Ws[fr * LDW + k0 + q * 8];
    bf16x8 b1 = *(const bf16x8*)&Ws[(16 + fr) * LDW + k0 + q * 8];
    acc[0] = __builtin_amdgcn_mfma_f32_16x16x32_bf16(a, b0, acc[0], 0, 0, 0);
    acc[1] = __builtin_amdgcn_mfma_f32_16x16x32_bf16(a, b1, acc[1], 0, 0, 0);
  }

  const int rbase = q * 4;
#pragma unroll
  for (int j = 0; j < 2; ++j) {
    const int gn = j * 16 + fr;
    const float bias = b2[gn];
#pragma unroll
    for (int r = 0; r < 4; ++r) {
      const int gm = m0 + rbase + r;
      Q[(size_t)gm * 32 + gn] = acc[j][r] + bias;
    }
  }
}

// ---------- launch ----------
extern "C" void kernel_launch(void* const* d_in, const int* in_sizes, int n_in,
                              void* d_out, int out_size, void* d_ws, size_t ws_size,
                              hipStream_t stream) {
  const float* obs  = (const float*)d_in[0];
  const float* act  = (const float*)d_in[1];
  const float* hid  = (const float*)d_in[2];
  const float* cell = (const float*)d_in[3];
  const float* W1   = (const float*)d_in[4];
  const float* b1   = (const float*)d_in[5];
  const float* Wih  = (const float*)d_in[6];
  const float* bih  = (const float*)d_in[7];
  const float* Whh  = (const float*)d_in[8];
  const float* bhh  = (const float*)d_in[9];
  const float* W2   = (const float*)d_in[10];
  const float* b2   = (const float*)d_in[11];
  float* out = (float*)d_out;

  char* ws = (char*)d_ws;
  unsigned short* H    = (unsigned short*)(ws);              // [B,512] bf16 (33,554,432 B)
  unsigned char*  X8   = (unsigned char*)(ws + 35651584);    // [B,512] fp8 tiled (16,777,216 B)
  unsigned short* W1b  = (unsigned short*)(ws + 52428800);   // 557,056 B
  unsigned char*  Wih8 = (unsigned char*)(ws + 52985856);    // 1,048,576 B
  unsigned short* W2b  = (unsigned short*)(ws + 54034432);   // 32,768 B
  float*          hvec = (float*)(ws + 54067200);            // 8,192 B

  prep_all<<<1824, 256, 0, stream>>>(W1, Wih, W2, Whh, hid, bhh, bih,
                                     W1b, Wih8, W2b, hvec);
  gemm1_relu<<<1024, 256, 0, stream>>>(obs, act, W1b, b1, X8);
  gemm2_lstm<<<2048, 256, 0, stream>>>(X8, Wih8, hvec, cell, H,
                                       out + 32768 * 32,
                                       out + 32768 * 32 + 512);
  gemm3<<<512, 256, 0, stream>>>(H, W2b, b2, out);
}